// Round 13
// baseline (1281.644 us; speedup 1.0000x reference)
//
#include <hip/hip_runtime.h>
#include <stdint.h>

#define NN 32768            // nodes
#define HID 512
#define EM 131072           // mol edges
#define EP 196608           // pro edges
#define AS1 __attribute__((address_space(1)))
#define AS3 __attribute__((address_space(3)))

typedef _Float16 h8 __attribute__((ext_vector_type(8)));
typedef float f4 __attribute__((ext_vector_type(4)));
typedef float f8 __attribute__((ext_vector_type(8)));

__device__ __forceinline__ void gload_lds16(const _Float16* g, _Float16* l) {
    __builtin_amdgcn_global_load_lds((AS1 void*)(g), (AS3 void*)(l), 16, 0, 0);
}

// ---------------- fused weight conversion: 12 transpose+cast jobs in one launch ----------------
struct ConvJobs {
    const float* src[12];
    _Float16* dst[12];
    int K[12], N[12], Kp[12];
    int blk0[13];
};

__global__ void conv_all(ConvJobs j) {
    int blk = blockIdx.x, job = 0;
    while (blk >= j.blk0[job + 1]) ++job;
    int idx = (blk - j.blk0[job]) * 256 + threadIdx.x;
    int Kp = j.Kp[job], N = j.N[job], K = j.K[job];
    if (idx >= N * Kp) return;
    int n = idx / Kp, k = idx - n * Kp;
    j.dst[job][idx] = (k < K) ? (_Float16)j.src[job][(size_t)k * N + n] : (_Float16)0.f;
}

// pad+cast features fp32 [NN,F] -> fp16 [NN,128]; z selects branch (combined mode)
__global__ void pad_x2(const float* s0, const float* s1, int F0, int F1, _Float16* dstb) {
    int z = blockIdx.z;
    const float* src = z ? s1 : s0;
    int F = z ? F1 : F0;
    _Float16* dst = dstb + (size_t)z * NN * 128;
    int idx = blockIdx.x * 256 + threadIdx.x;
    int i = idx >> 7, jj = idx & 127;
    dst[idx] = (jj < F) ? (_Float16)src[(size_t)i * F + jj] : (_Float16)0.f;
}

// ---------------- CSR build (both branches, meta arrays are [2][...]) ----------------
__global__ void init_deg(int* deg) {
    deg[(size_t)blockIdx.z * NN + blockIdx.x * 256 + threadIdx.x] = 1;  // self loop
}

__global__ void count_edges2(const int* c0, int E0, const int* c1, int E1, int* deg) {
    int i = blockIdx.x * 256 + threadIdx.x;
    if (i < E0) atomicAdd(&deg[c0[i]], 1);
    else { i -= E0; if (i < E1) atomicAdd(&deg[NN + c1[i]], 1); }
}

__global__ void compute_dis(const int* deg, float* dis) {
    int i = blockIdx.z * NN + blockIdx.x * 256 + threadIdx.x;
    dis[i] = rsqrtf((float)deg[i]);
}

__global__ void scan_offsets(const int* degb, int* offsb, int* curb) {
    const int* deg = degb + blockIdx.z * NN;
    int* offs = offsb + blockIdx.z * (NN + 1);
    int* cur = curb + blockIdx.z * NN;
    __shared__ int part[1024];
    int t = threadIdx.x, base = t * 32;
    int loc[32], sum = 0;
    for (int jj = 0; jj < 32; ++jj) { loc[jj] = sum; sum += deg[base + jj] - 1; }
    part[t] = sum;
    __syncthreads();
    for (int o = 1; o < 1024; o <<= 1) {
        int v = (t >= o) ? part[t - o] : 0;
        __syncthreads();
        part[t] += v;
        __syncthreads();
    }
    int pre = (t == 0) ? 0 : part[t - 1];
    for (int jj = 0; jj < 32; ++jj) { int x = pre + loc[jj]; offs[base + jj] = x; cur[base + jj] = x; }
    if (t == 1023) offs[NN] = part[1023];
}

__global__ void scatter2(const int* r0, const int* c0, int E0,
                         const int* r1, const int* c1, int E1,
                         int* cur, int* s0, int* s1) {
    int i = blockIdx.x * 256 + threadIdx.x;
    if (i < E0) { int p = atomicAdd(&cur[c0[i]], 1); s0[p] = r0[i]; }
    else { i -= E0; if (i < E1) { int p = atomicAdd(&cur[NN + c1[i]], 1); s1[p] = r1[i]; } }
}

// ---------------- fused layer: 64-row tile, 1024 threads, 2 blocks/CU (32 gather waves/CU) --
// Phase 1: 16 waves gather 4 rows each into LDS. Phase 2: barrier-free GEMM, wave tile 32x64
// (acc 2x4 keeps VGPR<=64 so 8 waves/EU => 2 blocks/CU). B from L2-hot global.
// Epilogue: pout = relu(sup + sup@W) + pin. Last layer: result -> LDS, then fused
// out-projection K=512 GEMM vs woutT -> xc.
#define ROWP 536
#define LROWS 64

struct LArgs {
    const _Float16* pin;
    const _Float16* h0;
    _Float16* pout;            // unused when woutT != null
    const float* dis;
    const int* offs;
    const int* sr0;
    const int* sr1;
    const _Float16* wT;        // layer weight base (layer offset applied), z-stride 3*512*512
    const _Float16* woutT;     // out-proj weights base (b0 offset applied), z-stride 128*512
    const float* bo[2];        // out-proj bias per branch slot (index mz)
    _Float16* xc;              // [NN, 256]
    size_t bstr;
    int mzadd;
};

__global__ __launch_bounds__(1024, 8) void layer_fused(LArgs a) {
    extern __shared__ _Float16 sup[];   // [64][ROWP]
    const int z = blockIdx.z, mz = z + a.mzadd;
    const _Float16* __restrict__ pin = a.pin + (size_t)z * a.bstr;
    const _Float16* __restrict__ h0 = a.h0 + (size_t)z * a.bstr;
    const _Float16* __restrict__ BT = a.wT + (size_t)z * (3 * 512 * 512);
    const float* __restrict__ dis = a.dis + mz * NN;
    const int* __restrict__ offs = a.offs + mz * (NN + 1);
    const int* __restrict__ srow = mz ? a.sr1 : a.sr0;
    const int tid = threadIdx.x, wave = tid >> 6, lane = tid & 63;
    const int row0 = blockIdx.x * LROWS;

    // ---- phase 1: gather 4 rows per wave; 4-wide independent-load batches ----
    for (int i = 0; i < 4; ++i) {
        const int rl = wave * 4 + i, row = row0 + rl;
        const int e0 = offs[row], e1 = offs[row + 1];
        f8 acg = {};
        for (int e = e0; e < e1; e += 4) {
            const int j1 = (e + 1 < e1) ? e + 1 : e;
            const int j2 = (e + 2 < e1) ? e + 2 : e;
            const int j3 = (e + 3 < e1) ? e + 3 : e;
            const float m1 = (e + 1 < e1) ? 1.f : 0.f;
            const float m2 = (e + 2 < e1) ? 1.f : 0.f;
            const float m3 = (e + 3 < e1) ? 1.f : 0.f;
            const int r0 = srow[e], r1 = srow[j1], r2 = srow[j2], r3 = srow[j3];
            const float s0 = dis[r0], s1 = dis[r1] * m1, s2 = dis[r2] * m2, s3 = dis[r3] * m3;
            h8 v0 = *(const h8*)&pin[(size_t)r0 * 512 + lane * 8];
            h8 v1 = *(const h8*)&pin[(size_t)r1 * 512 + lane * 8];
            h8 v2 = *(const h8*)&pin[(size_t)r2 * 512 + lane * 8];
            h8 v3 = *(const h8*)&pin[(size_t)r3 * 512 + lane * 8];
            acg += s0 * __builtin_convertvector(v0, f8) + s1 * __builtin_convertvector(v1, f8)
                 + s2 * __builtin_convertvector(v2, f8) + s3 * __builtin_convertvector(v3, f8);
        }
        const float si = dis[row];
        h8 pv = *(const h8*)&pin[(size_t)row * 512 + lane * 8];
        h8 hv = *(const h8*)&h0[(size_t)row * 512 + lane * 8];
        f8 r = 0.8f * si * (acg + si * __builtin_convertvector(pv, f8))
             + 0.2f * __builtin_convertvector(hv, f8);
        *(h8*)&sup[rl * ROWP + lane * 8] = __builtin_convertvector(r, h8);
    }
    __syncthreads();

    // ---- phase 2: barrier-free GEMM; 16 waves, wave tile 32x64 (2x4 frags) ----
    const int wm = wave & 1, wn = wave >> 1;          // wn in [0,8): 64-col slice
    const int l15 = lane & 15, lq = lane >> 4;
    f4 acc[2][4] = {};
    #pragma unroll
    for (int kt = 0; kt < 8; ++kt) {
        #pragma unroll
        for (int s = 0; s < 2; ++s) {
            const int koff = kt * 64 + s * 32 + lq * 8;
            h8 af[2], bf[4];
            #pragma unroll
            for (int rt = 0; rt < 2; ++rt)
                af[rt] = *(const h8*)&sup[(wm * 32 + rt * 16 + l15) * ROWP + koff];
            #pragma unroll
            for (int ct = 0; ct < 4; ++ct)
                bf[ct] = *(const h8*)(BT + (size_t)(wn * 64 + ct * 16 + l15) * 512 + koff);
            #pragma unroll
            for (int rt = 0; rt < 2; ++rt)
                #pragma unroll
                for (int ct = 0; ct < 4; ++ct)
                    acc[rt][ct] = __builtin_amdgcn_mfma_f32_16x16x32_f16(af[rt], bf[ct], acc[rt][ct], 0, 0, 0);
        }
    }
    const bool fuse_out = (a.woutT != nullptr);
    if (fuse_out) __syncthreads();   // all sup reads done before epilogue overwrites sup
    // ---- epilogue: nv = relu(sup + sup@W) + pin ----
    _Float16* __restrict__ pout = a.pout ? a.pout + (size_t)z * a.bstr : nullptr;
    #pragma unroll
    for (int rt = 0; rt < 2; ++rt) {
        #pragma unroll
        for (int ct = 0; ct < 4; ++ct) {
            const int col = wn * 64 + ct * 16 + l15;
            #pragma unroll
            for (int r = 0; r < 4; ++r) {
                const int rl = wm * 32 + rt * 16 + lq * 4 + r;
                const size_t gi = (size_t)(row0 + rl) * 512 + col;
                float nv = fmaxf((float)sup[rl * ROWP + col] + acc[rt][ct][r], 0.f) + (float)pin[gi];
                if (fuse_out) sup[rl * ROWP + col] = (_Float16)nv;  // own element
                else          pout[gi] = (_Float16)nv;
            }
        }
    }
    if (!fuse_out) return;

    // ---- fused out-projection: xc[:, mz*128 : +128] = sup_final @ woutT + bo ----
    __syncthreads();
    const _Float16* __restrict__ WO = a.woutT + (size_t)z * (128 * 512);
    const float* __restrict__ bo = a.bo[mz];
    f4 acc2[2] = {};                                  // 2 row frags x 1 col frag (16 cols/wave)
    #pragma unroll
    for (int kt = 0; kt < 8; ++kt) {
        #pragma unroll
        for (int s = 0; s < 2; ++s) {
            const int koff = kt * 64 + s * 32 + lq * 8;
            h8 af[2];
            #pragma unroll
            for (int rt = 0; rt < 2; ++rt)
                af[rt] = *(const h8*)&sup[(wm * 32 + rt * 16 + l15) * ROWP + koff];
            h8 bf = *(const h8*)(WO + (size_t)(wn * 16 + l15) * 512 + koff);
            #pragma unroll
            for (int rt = 0; rt < 2; ++rt)
                acc2[rt] = __builtin_amdgcn_mfma_f32_16x16x32_f16(af[rt], bf, acc2[rt], 0, 0, 0);
        }
    }
    #pragma unroll
    for (int rt = 0; rt < 2; ++rt) {
        const int col = wn * 16 + l15;
        #pragma unroll
        for (int r = 0; r < 4; ++r) {
            const int row = row0 + wm * 32 + rt * 16 + lq * 4 + r;
            a.xc[(size_t)row * 256 + mz * 128 + col] = (_Float16)(acc2[rt][r] + bo[col]);
        }
    }
}

// ---------------- staged-A barrier-free GEMM (K<=256): C = relu(A@B^T + bias) ---------------
struct GArgs {
    const _Float16* A[2];
    const _Float16* BT[2];
    const float* bias[2];
    _Float16* C[2];
    _Float16* C2[2];
};

template <int K>
__global__ __launch_bounds__(512, 4) void gemm_a1(GArgs g, int ldc) {
    constexpr int NK = K / 64;
    __shared__ _Float16 lA[NK * 8 * 128 * 8];
    const int z = blockIdx.z;
    const _Float16* __restrict__ A = g.A[z];
    const _Float16* __restrict__ BT = g.BT[z];
    const int tid = threadIdx.x, wave = tid >> 6, lane = tid & 63;
    const int row0 = blockIdx.x * 128, col0 = blockIdx.y * 256;
    const int wm = wave & 1, wn = wave >> 1;          // 8 waves: 2 x 4, wave tile 64x64
    const int l15 = lane & 15, lq = lane >> 4;
    constexpr int CNT = NK * 16 / 8;                  // staging instrs per wave
    #pragma unroll
    for (int q = 0; q < CNT; ++q) {
        const int c = wave * CNT + q;
        const int kc = c >> 4, rem = c & 15, k8 = rem & 7, rh = rem >> 3;
        gload_lds16(A + (size_t)(row0 + rh * 64 + lane) * K + kc * 64 + k8 * 8,
                    &lA[((kc * 8 + k8) * 128 + rh * 64) * 8]);
    }
    __syncthreads();
    f4 acc[4][4] = {};
    #pragma unroll
    for (int kt = 0; kt < NK; ++kt) {
        #pragma unroll
        for (int s = 0; s < 2; ++s) {
            const int kq = s * 4 + lq;
            h8 af[4], bf[4];
            #pragma unroll
            for (int rt = 0; rt < 4; ++rt)
                af[rt] = *(const h8*)&lA[((kt * 8 + kq) * 128 + wm * 64 + rt * 16 + l15) * 8];
            #pragma unroll
            for (int ct = 0; ct < 4; ++ct)
                bf[ct] = *(const h8*)(BT + (size_t)(col0 + wn * 64 + ct * 16 + l15) * K + kt * 64 + kq * 8);
            #pragma unroll
            for (int rt = 0; rt < 4; ++rt)
                #pragma unroll
                for (int ct = 0; ct < 4; ++ct)
                    acc[rt][ct] = __builtin_amdgcn_mfma_f32_16x16x32_f16(af[rt], bf[ct], acc[rt][ct], 0, 0, 0);
        }
    }
    #pragma unroll
    for (int rt = 0; rt < 4; ++rt) {
        #pragma unroll
        for (int ct = 0; ct < 4; ++ct) {
            const int col = col0 + wn * 64 + ct * 16 + l15;
            #pragma unroll
            for (int r = 0; r < 4; ++r) {
                const int row = row0 + wm * 64 + rt * 16 + lq * 4 + r;
                float v = fmaxf(acc[rt][ct][r] + g.bias[z][col], 0.f);
                g.C[z][(size_t)row * ldc + col] = (_Float16)v;
                if (g.C2[z]) g.C2[z][(size_t)row * ldc + col] = (_Float16)v;
            }
        }
    }
}

// ---------------- fc2 + final dot, staged-A barrier-free: out = relu(x1@fc2+b2).w_o + b_o --
// 64-row A slab [64,1024] = 128 KB LDS staged once; ONE barrier; K-loop B from L2-hot fc2T.
__global__ __launch_bounds__(512, 2) void gemm_fc2f(
    const _Float16* __restrict__ A, const _Float16* __restrict__ BT,
    const float* __restrict__ b2, const float* __restrict__ wo,
    const float* __restrict__ bo, float* __restrict__ out) {
    extern __shared__ _Float16 lA[];                  // [128 k-octs][64 rows][8]
    const int tid = threadIdx.x, wave = tid >> 6, lane = tid & 63;
    const int row0 = blockIdx.x * 64;
    const int wm = wave & 1, wn = wave >> 1;          // 8 waves: 2 x 4; wave tile 32x128
    const int l15 = lane & 15, lq = lane >> 4;
    // stage: 128 k-octs x 64 rows; 16 octs per wave
    #pragma unroll
    for (int q = 0; q < 16; ++q) {
        const int c = wave * 16 + q;                  // k-oct index
        gload_lds16(A + (size_t)(row0 + lane) * 1024 + c * 8, &lA[(c * 64) * 8]);
    }
    __syncthreads();
    f4 acc[2][8] = {};
    #pragma unroll
    for (int kt = 0; kt < 32; ++kt) {                 // K = 1024, 32-wide steps
        const int ko = kt * 4 + lq;
        h8 af[2], bf[8];
        #pragma unroll
        for (int rt = 0; rt < 2; ++rt)
            af[rt] = *(const h8*)&lA[(ko * 64 + wm * 32 + rt * 16 + l15) * 8];
        #pragma unroll
        for (int ct = 0; ct < 8; ++ct)
            bf[ct] = *(const h8*)(BT + (size_t)(wn * 128 + ct * 16 + l15) * 1024 + kt * 32 + lq * 8);
        #pragma unroll
        for (int rt = 0; rt < 2; ++rt)
            #pragma unroll
            for (int ct = 0; ct < 8; ++ct)
                acc[rt][ct] = __builtin_amdgcn_mfma_f32_16x16x32_f16(af[rt], bf[ct], acc[rt][ct], 0, 0, 0);
    }
    // epilogue: per-row partial dot with w_o over this wave's 128 cols; 16-lane reduce; atomic
    #pragma unroll
    for (int rt = 0; rt < 2; ++rt) {
        #pragma unroll
        for (int r = 0; r < 4; ++r) {
            float p = 0.f;
            #pragma unroll
            for (int ct = 0; ct < 8; ++ct) {
                const int colg = wn * 128 + ct * 16 + l15;
                float v = fmaxf(acc[rt][ct][r] + b2[colg], 0.f);
                p += v * wo[colg];
            }
            p += __shfl_xor(p, 1); p += __shfl_xor(p, 2);
            p += __shfl_xor(p, 4); p += __shfl_xor(p, 8);
            if (l15 == 0) {
                const int row = row0 + wm * 32 + rt * 16 + lq * 4 + r;
                if (wn == 0) p += bo[0];
                atomicAdd(&out[row], p);
            }
        }
    }
}

// ---------------- workspace plan ----------------
struct WS {
    int *deg, *offs, *cur, *srow0, *srow1;
    float* dis;
    _Float16 *winT, *wsT, *woutT, *fc1T, *fc2T;
    _Float16 *xpad, *h0, *prev0, *prev1, *xc;
    size_t total;
};

static WS plan(char* base, bool comb) {
    size_t off = 0;
    auto al = [&](size_t n) { off = (off + 255) & ~(size_t)255; size_t o = off; off += n; return base + o; };
    WS w;
    w.deg   = (int*)al(2 * NN * 4);
    w.dis   = (float*)al(2 * NN * 4);
    w.offs  = (int*)al(2 * (NN + 1) * 4);
    w.cur   = (int*)al(2 * NN * 4);
    w.srow0 = (int*)al((size_t)EM * 4);
    w.srow1 = (int*)al((size_t)EP * 4);
    w.winT  = (_Float16*)al(2 * 512 * 128 * 2);
    w.wsT   = (_Float16*)al((size_t)2 * 3 * 512 * 512 * 2);
    w.woutT = (_Float16*)al(2 * 128 * 512 * 2);
    w.fc1T  = (_Float16*)al(1024 * 256 * 2);
    w.fc2T  = (_Float16*)al((size_t)512 * 1024 * 2);
    const size_t nb = comb ? 2 : 1;
    const size_t HB = (size_t)NN * HID * 2;      // 32 MB, 256-aligned -> h0/prev0 contiguous
    w.xpad  = (_Float16*)al(nb * NN * 128 * 2);
    w.h0    = (_Float16*)al(nb * HB);            // reused as x1 [NN,1024] in the head
    w.prev0 = (_Float16*)al(nb * HB);
    w.prev1 = (_Float16*)al(nb * HB);
    w.xc    = (_Float16*)al((size_t)NN * 256 * 2);
    w.total = off;
    return w;
}

// ---------------- host orchestration ----------------
extern "C" void kernel_launch(void* const* d_in, const int* in_sizes, int n_in,
                              void* d_out, int out_size, void* d_ws, size_t ws_size,
                              hipStream_t stream) {
    const float* mol_x   = (const float*)d_in[0];
    const int*   mol_ei  = (const int*)d_in[1];
    const float* pro_x   = (const float*)d_in[2];
    const int*   pro_ei  = (const int*)d_in[3];
    const float* win[2]  = {(const float*)d_in[4], (const float*)d_in[9]};
    const float* bin[2]  = {(const float*)d_in[5], (const float*)d_in[10]};
    const float* ws3[2]  = {(const float*)d_in[6], (const float*)d_in[11]};
    const float* wo[2]   = {(const float*)d_in[7], (const float*)d_in[12]};
    const float* bo[2]   = {(const float*)d_in[8], (const float*)d_in[13]};
    const float* w_fc1   = (const float*)d_in[14];
    const float* b_fc1   = (const float*)d_in[15];
    const float* w_fc2   = (const float*)d_in[16];
    const float* b_fc2   = (const float*)d_in[17];
    const float* w_o     = (const float*)d_in[18];
    const float* b_o     = (const float*)d_in[19];
    const int F[2] = {78, 54};

    char* wsb = (char*)d_ws;
    WS w = plan(wsb, true);
    const bool comb = (w.total <= ws_size);
    if (!comb) w = plan(wsb, false);
    const size_t BSTR = comb ? (size_t)NN * HID : 0;
    const size_t XSTR = comb ? (size_t)NN * 128 : 0;
    const int LDSB = LROWS * ROWP * 2;              // 68608 B dynamic LDS -> 2 blocks/CU
    const int LDSF = 64 * 1024 * 2;                 // 131072 B for fc2f A-slab

    hipFuncSetAttribute((const void*)layer_fused,
                        hipFuncAttributeMaxDynamicSharedMemorySize, LDSB);
    hipFuncSetAttribute((const void*)gemm_fc2f,
                        hipFuncAttributeMaxDynamicSharedMemorySize, LDSF);

    // --- 1. weight conversions (12 jobs, one launch) ---
    ConvJobs j;
    int nblk = 0, ji = 0;
    auto addjob = [&](const float* s, _Float16* d, int K, int N, int Kp) {
        j.src[ji] = s; j.dst[ji] = d; j.K[ji] = K; j.N[ji] = N; j.Kp[ji] = Kp;
        j.blk0[ji] = nblk; nblk += (N * Kp + 255) / 256; ++ji;
    };
    for (int b = 0; b < 2; ++b) addjob(win[b], w.winT + b * 512 * 128, F[b], 512, 128);
    for (int b = 0; b < 2; ++b)
        for (int l = 0; l < 3; ++l)
            addjob(ws3[b] + (size_t)l * 512 * 512,
                   w.wsT + ((size_t)b * 3 + l) * 512 * 512, 512, 512, 512);
    for (int b = 0; b < 2; ++b) addjob(wo[b], w.woutT + b * 128 * 512, 512, 128, 512);
    addjob(w_fc1, w.fc1T, 256, 1024, 256);
    addjob(w_fc2, w.fc2T, 1024, 512, 1024);
    j.blk0[12] = nblk;
    conv_all<<<nblk, 256, 0, stream>>>(j);

    // --- 2. CSR build ---
    init_deg<<<dim3(NN / 256, 1, 2), 256, 0, stream>>>(w.deg);
    count_edges2<<<(EM + EP + 255) / 256, 256, 0, stream>>>(mol_ei + EM, EM, pro_ei + EP, EP, w.deg);
    compute_dis<<<dim3(NN / 256, 1, 2), 256, 0, stream>>>(w.deg, w.dis);
    scan_offsets<<<dim3(1, 1, 2), 1024, 0, stream>>>(w.deg, w.offs, w.cur);
    scatter2<<<(EM + EP + 255) / 256, 256, 0, stream>>>(mol_ei, mol_ei + EM, EM,
                                                        pro_ei, pro_ei + EP, EP,
                                                        w.cur, w.srow0, w.srow1);

    // --- 3. branches: input GEMM + 3 fused layers (last layer fuses out-projection) ---
    auto branch_chain = [&](int zcount, int b0) {
        GArgs g{};
        for (int z = 0; z < zcount; ++z) {
            int b = b0 + z;
            g.A[z] = w.xpad + z * XSTR;
            g.BT[z] = w.winT + b * 512 * 128;
            g.bias[z] = bin[b];
            g.C[z] = w.h0 + z * BSTR;
            g.C2[z] = w.prev0 + z * BSTR;
        }
        gemm_a1<128><<<dim3(256, 2, zcount), 512, 0, stream>>>(g, HID);
        _Float16* pp[2] = {w.prev0, w.prev1};
        for (int l = 0; l < 3; ++l) {
            LArgs a{};
            a.pin = pp[l & 1];
            a.h0 = w.h0;
            a.pout = (l == 2) ? nullptr : pp[(l & 1) ^ 1];
            a.dis = w.dis; a.offs = w.offs; a.sr0 = w.srow0; a.sr1 = w.srow1;
            a.wT = w.wsT + ((size_t)b0 * 3 + l) * 512 * 512;
            a.woutT = (l == 2) ? (w.woutT + (size_t)b0 * 128 * 512) : nullptr;
            a.bo[0] = bo[0]; a.bo[1] = bo[1];
            a.xc = w.xc;
            a.bstr = BSTR; a.mzadd = b0;
            layer_fused<<<dim3(NN / LROWS, 1, zcount), 1024, LDSB, stream>>>(a);
        }
    };

    if (comb) {
        pad_x2<<<dim3(NN * 128 / 256, 1, 2), 256, 0, stream>>>(mol_x, pro_x, F[0], F[1], w.xpad);
        branch_chain(2, 0);
    } else {
        for (int b = 0; b < 2; ++b) {
            pad_x2<<<dim3(NN * 128 / 256, 1, 1), 256, 0, stream>>>(
                b ? pro_x : mol_x, nullptr, F[b], 0, w.xpad);
            branch_chain(1, b);
        }
    }

    // --- 4. MLP head: x1 = relu(xc@fc1+b1); out = relu(x1@fc2+b2).w_o + b_o (fused) ---
    _Float16* x1 = w.h0;    // [NN,1024]: comb -> h0 block (64MB); fallback -> h0+prev0 contiguous
    GArgs g1{};
    g1.A[0] = w.xc; g1.BT[0] = w.fc1T; g1.bias[0] = b_fc1; g1.C[0] = x1; g1.C2[0] = nullptr;
    gemm_a1<256><<<dim3(256, 4, 1), 512, 0, stream>>>(g1, 1024);
    hipMemsetAsync(d_out, 0, (size_t)NN * 4, stream);   // harness poisons d_out to 0xAA
    gemm_fc2f<<<dim3(NN / 64, 1), 512, LDSF, stream>>>(x1, w.fc2T, b_fc2, w_o, b_o, (float*)d_out);
    (void)in_sizes; (void)n_in; (void)out_size; (void)ws_size;
}

// Round 14
// 909.309 us; speedup vs baseline: 1.4095x; 1.4095x over previous
//
#include <hip/hip_runtime.h>
#include <stdint.h>

#define NN 32768            // nodes
#define HID 512
#define EM 131072           // mol edges
#define EP 196608           // pro edges
#define AS1 __attribute__((address_space(1)))
#define AS3 __attribute__((address_space(3)))

typedef _Float16 h8 __attribute__((ext_vector_type(8)));
typedef float f4 __attribute__((ext_vector_type(4)));
typedef float f8 __attribute__((ext_vector_type(8)));

__device__ __forceinline__ void gload_lds16(const _Float16* g, _Float16* l) {
    __builtin_amdgcn_global_load_lds((AS1 void*)(g), (AS3 void*)(l), 16, 0, 0);
}

// ---------------- fused weight conversion: LDS-tiled transpose+cast, 12 jobs, one launch ----
// dst fp16 [N, Kp] = transpose(src fp32 [K, N]), zero-padded K->Kp. Both phases coalesced.
struct ConvJobs {
    const float* src[12];
    _Float16* dst[12];
    int K[12], N[12], Kp[12];
    int blk0[13];   // cumulative 32x32-tile starts
};

__global__ void conv_all(ConvJobs j) {
    __shared__ float tile[32][33];
    int blk = blockIdx.x, job = 0;
    while (blk >= j.blk0[job + 1]) ++job;
    int t = blk - j.blk0[job];
    int Kp = j.Kp[job], N = j.N[job], K = j.K[job];
    int ktiles = Kp >> 5;
    int n0 = (t / ktiles) << 5, k0 = (t % ktiles) << 5;
    int tn = threadIdx.x & 31, tr = threadIdx.x >> 5;
    const float* src = j.src[job];
    #pragma unroll
    for (int p = 0; p < 4; ++p) {
        int k = k0 + tr + p * 8;
        tile[tr + p * 8][tn] = (k < K) ? src[(size_t)k * N + n0 + tn] : 0.f;
    }
    __syncthreads();
    _Float16* dst = j.dst[job];
    #pragma unroll
    for (int p = 0; p < 4; ++p) {
        int nl = tr + p * 8;
        dst[(size_t)(n0 + nl) * Kp + k0 + tn] = (_Float16)tile[tn][nl];
    }
}

// pad+cast features fp32 [NN,F] -> fp16 [NN,128]; z selects branch (combined mode)
__global__ void pad_x2(const float* s0, const float* s1, int F0, int F1, _Float16* dstb) {
    int z = blockIdx.z;
    const float* src = z ? s1 : s0;
    int F = z ? F1 : F0;
    _Float16* dst = dstb + (size_t)z * NN * 128;
    int idx = blockIdx.x * 256 + threadIdx.x;
    int i = idx >> 7, jj = idx & 127;
    dst[idx] = (jj < F) ? (_Float16)src[(size_t)i * F + jj] : (_Float16)0.f;
}

// ---------------- CSR build (both branches, meta arrays are [2][...]) ----------------
__global__ void init_deg(int* deg) {
    deg[(size_t)blockIdx.z * NN + blockIdx.x * 256 + threadIdx.x] = 1;  // self loop
}

__global__ void count_edges2(const int* c0, int E0, const int* c1, int E1, int* deg) {
    int i = blockIdx.x * 256 + threadIdx.x;
    if (i < E0) atomicAdd(&deg[c0[i]], 1);
    else { i -= E0; if (i < E1) atomicAdd(&deg[NN + c1[i]], 1); }
}

// exclusive scan of (deg-1) + dis = rsqrt(deg); one block per branch (blockIdx.z)
__global__ void scan_offsets(const int* degb, int* offsb, int* curb, float* disb) {
    const int* deg = degb + blockIdx.z * NN;
    int* offs = offsb + blockIdx.z * (NN + 1);
    int* cur = curb + blockIdx.z * NN;
    float* dis = disb + blockIdx.z * NN;
    __shared__ int part[1024];
    int t = threadIdx.x, base = t * 32;
    int loc[32], sum = 0;
    for (int jj = 0; jj < 32; ++jj) {
        int d = deg[base + jj];
        dis[base + jj] = rsqrtf((float)d);
        loc[jj] = sum; sum += d - 1;
    }
    part[t] = sum;
    __syncthreads();
    for (int o = 1; o < 1024; o <<= 1) {
        int v = (t >= o) ? part[t - o] : 0;
        __syncthreads();
        part[t] += v;
        __syncthreads();
    }
    int pre = (t == 0) ? 0 : part[t - 1];
    for (int jj = 0; jj < 32; ++jj) { int x = pre + loc[jj]; offs[base + jj] = x; cur[base + jj] = x; }
    if (t == 1023) offs[NN] = part[1023];
}

__global__ void scatter2(const int* r0, const int* c0, int E0,
                         const int* r1, const int* c1, int E1,
                         int* cur, int* s0, int* s1) {
    int i = blockIdx.x * 256 + threadIdx.x;
    if (i < E0) { int p = atomicAdd(&cur[c0[i]], 1); s0[p] = r0[i]; }
    else { i -= E0; if (i < E1) { int p = atomicAdd(&cur[NN + c1[i]], 1); s1[p] = r1[i]; } }
}

// ---------------- fused layer: 128-row tile, 1024 threads (R12 config, traffic-minimal) ----
// Phase 1: 16 waves gather 8 rows each into LDS. Phase 2: barrier-free GEMM, wave tile 64x64;
// B from L2-hot global. Epilogue: pout = relu(sup + sup@W) + pin. Last layer: result -> LDS,
// then fused out-projection K=512 GEMM vs woutT -> xc.
#define ROWP 536

struct LArgs {
    const _Float16* pin;
    const _Float16* h0;
    _Float16* pout;            // unused when woutT != null
    const float* dis;
    const int* offs;
    const int* sr0;
    const int* sr1;
    const _Float16* wT;        // layer weight base (layer offset applied), z-stride 3*512*512
    const _Float16* woutT;     // out-proj weights base (b0 offset applied), z-stride 128*512
    const float* bo[2];        // out-proj bias per branch slot (index mz)
    _Float16* xc;              // [NN, 256]
    size_t bstr;
    int mzadd;
};

__global__ __launch_bounds__(1024, 4) void layer_fused(LArgs a) {
    extern __shared__ _Float16 sup[];   // [128][ROWP]
    const int z = blockIdx.z, mz = z + a.mzadd;
    const _Float16* __restrict__ pin = a.pin + (size_t)z * a.bstr;
    const _Float16* __restrict__ h0 = a.h0 + (size_t)z * a.bstr;
    const _Float16* __restrict__ BT = a.wT + (size_t)z * (3 * 512 * 512);
    const float* __restrict__ dis = a.dis + mz * NN;
    const int* __restrict__ offs = a.offs + mz * (NN + 1);
    const int* __restrict__ srow = mz ? a.sr1 : a.sr0;
    const int tid = threadIdx.x, wave = tid >> 6, lane = tid & 63;
    const int row0 = blockIdx.x * 128;

    // ---- phase 1: gather 8 rows per wave; 4-wide independent-load batches ----
    for (int i = 0; i < 8; ++i) {
        const int rl = wave * 8 + i, row = row0 + rl;
        const int e0 = offs[row], e1 = offs[row + 1];
        f8 acg = {};
        for (int e = e0; e < e1; e += 4) {
            const int j1 = (e + 1 < e1) ? e + 1 : e;
            const int j2 = (e + 2 < e1) ? e + 2 : e;
            const int j3 = (e + 3 < e1) ? e + 3 : e;
            const float m1 = (e + 1 < e1) ? 1.f : 0.f;
            const float m2 = (e + 2 < e1) ? 1.f : 0.f;
            const float m3 = (e + 3 < e1) ? 1.f : 0.f;
            const int r0 = srow[e], r1 = srow[j1], r2 = srow[j2], r3 = srow[j3];
            const float s0 = dis[r0], s1 = dis[r1] * m1, s2 = dis[r2] * m2, s3 = dis[r3] * m3;
            h8 v0 = *(const h8*)&pin[(size_t)r0 * 512 + lane * 8];
            h8 v1 = *(const h8*)&pin[(size_t)r1 * 512 + lane * 8];
            h8 v2 = *(const h8*)&pin[(size_t)r2 * 512 + lane * 8];
            h8 v3 = *(const h8*)&pin[(size_t)r3 * 512 + lane * 8];
            acg += s0 * __builtin_convertvector(v0, f8) + s1 * __builtin_convertvector(v1, f8)
                 + s2 * __builtin_convertvector(v2, f8) + s3 * __builtin_convertvector(v3, f8);
        }
        const float si = dis[row];
        h8 pv = *(const h8*)&pin[(size_t)row * 512 + lane * 8];
        h8 hv = *(const h8*)&h0[(size_t)row * 512 + lane * 8];
        f8 r = 0.8f * si * (acg + si * __builtin_convertvector(pv, f8))
             + 0.2f * __builtin_convertvector(hv, f8);
        *(h8*)&sup[rl * ROWP + lane * 8] = __builtin_convertvector(r, h8);
    }
    __syncthreads();

    // ---- phase 2: barrier-free GEMM; 16 waves, wave tile 64x64 (4x4 frags) ----
    const int wm = wave & 1, wn = wave >> 1;          // wn in [0,8): 64-col slice
    const int l15 = lane & 15, lq = lane >> 4;
    f4 acc[4][4] = {};
    #pragma unroll
    for (int kt = 0; kt < 8; ++kt) {
        #pragma unroll
        for (int s = 0; s < 2; ++s) {
            const int koff = kt * 64 + s * 32 + lq * 8;
            h8 af[4], bf[4];
            #pragma unroll
            for (int rt = 0; rt < 4; ++rt)
                af[rt] = *(const h8*)&sup[(wm * 64 + rt * 16 + l15) * ROWP + koff];
            #pragma unroll
            for (int ct = 0; ct < 4; ++ct)
                bf[ct] = *(const h8*)(BT + (size_t)(wn * 64 + ct * 16 + l15) * 512 + koff);
            #pragma unroll
            for (int rt = 0; rt < 4; ++rt)
                #pragma unroll
                for (int ct = 0; ct < 4; ++ct)
                    acc[rt][ct] = __builtin_amdgcn_mfma_f32_16x16x32_f16(af[rt], bf[ct], acc[rt][ct], 0, 0, 0);
        }
    }
    const bool fuse_out = (a.woutT != nullptr);
    if (fuse_out) __syncthreads();   // all sup reads done before epilogue overwrites sup
    // ---- epilogue: nv = relu(sup + sup@W) + pin ----
    _Float16* __restrict__ pout = a.pout ? a.pout + (size_t)z * a.bstr : nullptr;
    #pragma unroll
    for (int rt = 0; rt < 4; ++rt) {
        #pragma unroll
        for (int ct = 0; ct < 4; ++ct) {
            const int col = wn * 64 + ct * 16 + l15;
            #pragma unroll
            for (int r = 0; r < 4; ++r) {
                const int rl = wm * 64 + rt * 16 + lq * 4 + r;
                const size_t gi = (size_t)(row0 + rl) * 512 + col;
                float nv = fmaxf((float)sup[rl * ROWP + col] + acc[rt][ct][r], 0.f) + (float)pin[gi];
                if (fuse_out) sup[rl * ROWP + col] = (_Float16)nv;  // own element
                else          pout[gi] = (_Float16)nv;
            }
        }
    }
    if (!fuse_out) return;

    // ---- fused out-projection: xc[:, mz*128 : +128] = sup_final @ woutT + bo ----
    __syncthreads();
    const _Float16* __restrict__ WO = a.woutT + (size_t)z * (128 * 512);
    const float* __restrict__ bo = a.bo[mz];
    f4 acc2[4] = {};                                  // 4 row frags x 1 col frag (16 cols/wave)
    #pragma unroll
    for (int kt = 0; kt < 8; ++kt) {
        #pragma unroll
        for (int s = 0; s < 2; ++s) {
            const int koff = kt * 64 + s * 32 + lq * 8;
            h8 af[4];
            #pragma unroll
            for (int rt = 0; rt < 4; ++rt)
                af[rt] = *(const h8*)&sup[(wm * 64 + rt * 16 + l15) * ROWP + koff];
            h8 bf = *(const h8*)(WO + (size_t)(wn * 16 + l15) * 512 + koff);
            #pragma unroll
            for (int rt = 0; rt < 4; ++rt)
                acc2[rt] = __builtin_amdgcn_mfma_f32_16x16x32_f16(af[rt], bf, acc2[rt], 0, 0, 0);
        }
    }
    #pragma unroll
    for (int rt = 0; rt < 4; ++rt) {
        const int col = wn * 16 + l15;
        #pragma unroll
        for (int r = 0; r < 4; ++r) {
            const int row = row0 + wm * 64 + rt * 16 + lq * 4 + r;
            a.xc[(size_t)row * 256 + mz * 128 + col] = (_Float16)(acc2[rt][r] + bo[col]);
        }
    }
}

// ---------------- staged-A barrier-free GEMM (K<=256): C = relu(A@B^T + bias) ---------------
struct GArgs {
    const _Float16* A[2];
    const _Float16* BT[2];
    const float* bias[2];
    _Float16* C[2];
    _Float16* C2[2];
};

template <int K>
__global__ __launch_bounds__(512, 4) void gemm_a1(GArgs g, int ldc) {
    constexpr int NK = K / 64;
    __shared__ _Float16 lA[NK * 8 * 128 * 8];
    const int z = blockIdx.z;
    const _Float16* __restrict__ A = g.A[z];
    const _Float16* __restrict__ BT = g.BT[z];
    const int tid = threadIdx.x, wave = tid >> 6, lane = tid & 63;
    const int row0 = blockIdx.x * 128, col0 = blockIdx.y * 256;
    const int wm = wave & 1, wn = wave >> 1;          // 8 waves: 2 x 4, wave tile 64x64
    const int l15 = lane & 15, lq = lane >> 4;
    constexpr int CNT = NK * 16 / 8;                  // staging instrs per wave
    #pragma unroll
    for (int q = 0; q < CNT; ++q) {
        const int c = wave * CNT + q;
        const int kc = c >> 4, rem = c & 15, k8 = rem & 7, rh = rem >> 3;
        gload_lds16(A + (size_t)(row0 + rh * 64 + lane) * K + kc * 64 + k8 * 8,
                    &lA[((kc * 8 + k8) * 128 + rh * 64) * 8]);
    }
    __syncthreads();
    f4 acc[4][4] = {};
    #pragma unroll
    for (int kt = 0; kt < NK; ++kt) {
        #pragma unroll
        for (int s = 0; s < 2; ++s) {
            const int kq = s * 4 + lq;
            h8 af[4], bf[4];
            #pragma unroll
            for (int rt = 0; rt < 4; ++rt)
                af[rt] = *(const h8*)&lA[((kt * 8 + kq) * 128 + wm * 64 + rt * 16 + l15) * 8];
            #pragma unroll
            for (int ct = 0; ct < 4; ++ct)
                bf[ct] = *(const h8*)(BT + (size_t)(col0 + wn * 64 + ct * 16 + l15) * K + kt * 64 + kq * 8);
            #pragma unroll
            for (int rt = 0; rt < 4; ++rt)
                #pragma unroll
                for (int ct = 0; ct < 4; ++ct)
                    acc[rt][ct] = __builtin_amdgcn_mfma_f32_16x16x32_f16(af[rt], bf[ct], acc[rt][ct], 0, 0, 0);
        }
    }
    #pragma unroll
    for (int rt = 0; rt < 4; ++rt) {
        #pragma unroll
        for (int ct = 0; ct < 4; ++ct) {
            const int col = col0 + wn * 64 + ct * 16 + l15;
            #pragma unroll
            for (int r = 0; r < 4; ++r) {
                const int row = row0 + wm * 64 + rt * 16 + lq * 4 + r;
                float v = fmaxf(acc[rt][ct][r] + g.bias[z][col], 0.f);
                g.C[z][(size_t)row * ldc + col] = (_Float16)v;
                if (g.C2[z]) g.C2[z][(size_t)row * ldc + col] = (_Float16)v;
            }
        }
    }
}

// ---------------- fc2 + final dot, staged-A barrier-free, deterministic LDS reduction ------
// 64-row A slab [64,1024] = 128 KB LDS staged once; ONE barrier; K-loop B from L2-hot fc2T.
// out[row] = sum over 4 waves' 128-col partials (LDS reduce) -- no atomics, no memset needed.
__global__ __launch_bounds__(512, 2) void gemm_fc2f(
    const _Float16* __restrict__ A, const _Float16* __restrict__ BT,
    const float* __restrict__ b2, const float* __restrict__ wo,
    const float* __restrict__ bo, float* __restrict__ out) {
    extern __shared__ _Float16 lA[];                  // [128 k-octs][64 rows][8] + part[64][4]
    float* part = (float*)(lA + 64 * 1024);
    const int tid = threadIdx.x, wave = tid >> 6, lane = tid & 63;
    const int row0 = blockIdx.x * 64;
    const int wm = wave & 1, wn = wave >> 1;          // 8 waves: 2 x 4; wave tile 32x128
    const int l15 = lane & 15, lq = lane >> 4;
    #pragma unroll
    for (int q = 0; q < 16; ++q) {
        const int c = wave * 16 + q;                  // k-oct index
        gload_lds16(A + (size_t)(row0 + lane) * 1024 + c * 8, &lA[(c * 64) * 8]);
    }
    __syncthreads();
    f4 acc[2][8] = {};
    #pragma unroll
    for (int kt = 0; kt < 32; ++kt) {                 // K = 1024, 32-wide steps
        const int ko = kt * 4 + lq;
        h8 af[2], bf[8];
        #pragma unroll
        for (int rt = 0; rt < 2; ++rt)
            af[rt] = *(const h8*)&lA[(ko * 64 + wm * 32 + rt * 16 + l15) * 8];
        #pragma unroll
        for (int ct = 0; ct < 8; ++ct)
            bf[ct] = *(const h8*)(BT + (size_t)(wn * 128 + ct * 16 + l15) * 1024 + kt * 32 + lq * 8);
        #pragma unroll
        for (int rt = 0; rt < 2; ++rt)
            #pragma unroll
            for (int ct = 0; ct < 8; ++ct)
                acc[rt][ct] = __builtin_amdgcn_mfma_f32_16x16x32_f16(af[rt], bf[ct], acc[rt][ct], 0, 0, 0);
    }
    // per-row partial dot with w_o over this wave's 128 cols; 16-lane reduce; LDS part
    #pragma unroll
    for (int rt = 0; rt < 2; ++rt) {
        #pragma unroll
        for (int r = 0; r < 4; ++r) {
            float p = 0.f;
            #pragma unroll
            for (int ct = 0; ct < 8; ++ct) {
                const int colg = wn * 128 + ct * 16 + l15;
                float v = fmaxf(acc[rt][ct][r] + b2[colg], 0.f);
                p += v * wo[colg];
            }
            p += __shfl_xor(p, 1); p += __shfl_xor(p, 2);
            p += __shfl_xor(p, 4); p += __shfl_xor(p, 8);
            if (l15 == 0) {
                const int rl = wm * 32 + rt * 16 + lq * 4 + r;
                part[rl * 4 + wn] = p;
            }
        }
    }
    __syncthreads();
    if (tid < 64)
        out[row0 + tid] = part[tid * 4] + part[tid * 4 + 1] + part[tid * 4 + 2]
                        + part[tid * 4 + 3] + bo[0];
}

// ---------------- workspace plan ----------------
struct WS {
    int *deg, *offs, *cur, *srow0, *srow1;
    float* dis;
    _Float16 *winT, *wsT, *woutT, *fc1T, *fc2T;
    _Float16 *xpad, *h0, *prev0, *prev1, *xc;
    size_t total;
};

static WS plan(char* base, bool comb) {
    size_t off = 0;
    auto al = [&](size_t n) { off = (off + 255) & ~(size_t)255; size_t o = off; off += n; return base + o; };
    WS w;
    w.deg   = (int*)al(2 * NN * 4);
    w.dis   = (float*)al(2 * NN * 4);
    w.offs  = (int*)al(2 * (NN + 1) * 4);
    w.cur   = (int*)al(2 * NN * 4);
    w.srow0 = (int*)al((size_t)EM * 4);
    w.srow1 = (int*)al((size_t)EP * 4);
    w.winT  = (_Float16*)al(2 * 512 * 128 * 2);
    w.wsT   = (_Float16*)al((size_t)2 * 3 * 512 * 512 * 2);
    w.woutT = (_Float16*)al(2 * 128 * 512 * 2);
    w.fc1T  = (_Float16*)al(1024 * 256 * 2);
    w.fc2T  = (_Float16*)al((size_t)512 * 1024 * 2);
    const size_t nb = comb ? 2 : 1;
    const size_t HB = (size_t)NN * HID * 2;      // 32 MB, 256-aligned -> h0/prev0 contiguous
    w.xpad  = (_Float16*)al(nb * NN * 128 * 2);
    w.h0    = (_Float16*)al(nb * HB);            // reused as x1 [NN,1024] in the head
    w.prev0 = (_Float16*)al(nb * HB);
    w.prev1 = (_Float16*)al(nb * HB);
    w.xc    = (_Float16*)al((size_t)NN * 256 * 2);
    w.total = off;
    return w;
}

// ---------------- host orchestration ----------------
extern "C" void kernel_launch(void* const* d_in, const int* in_sizes, int n_in,
                              void* d_out, int out_size, void* d_ws, size_t ws_size,
                              hipStream_t stream) {
    const float* mol_x   = (const float*)d_in[0];
    const int*   mol_ei  = (const int*)d_in[1];
    const float* pro_x   = (const float*)d_in[2];
    const int*   pro_ei  = (const int*)d_in[3];
    const float* win[2]  = {(const float*)d_in[4], (const float*)d_in[9]};
    const float* bin[2]  = {(const float*)d_in[5], (const float*)d_in[10]};
    const float* ws3[2]  = {(const float*)d_in[6], (const float*)d_in[11]};
    const float* wo[2]   = {(const float*)d_in[7], (const float*)d_in[12]};
    const float* bo[2]   = {(const float*)d_in[8], (const float*)d_in[13]};
    const float* w_fc1   = (const float*)d_in[14];
    const float* b_fc1   = (const float*)d_in[15];
    const float* w_fc2   = (const float*)d_in[16];
    const float* b_fc2   = (const float*)d_in[17];
    const float* w_o     = (const float*)d_in[18];
    const float* b_o     = (const float*)d_in[19];
    const int F[2] = {78, 54};

    char* wsb = (char*)d_ws;
    WS w = plan(wsb, true);
    const bool comb = (w.total <= ws_size);
    if (!comb) w = plan(wsb, false);
    const size_t BSTR = comb ? (size_t)NN * HID : 0;
    const size_t XSTR = comb ? (size_t)NN * 128 : 0;
    const int LDSB = 128 * ROWP * 2;                // 137216 B dynamic LDS (1 block/CU)
    const int LDSF = 64 * 1024 * 2 + 64 * 4 * 4;    // fc2f A-slab + part[64][4]

    hipFuncSetAttribute((const void*)layer_fused,
                        hipFuncAttributeMaxDynamicSharedMemorySize, LDSB);
    hipFuncSetAttribute((const void*)gemm_fc2f,
                        hipFuncAttributeMaxDynamicSharedMemorySize, LDSF);

    // --- 1. weight conversions (12 jobs, one launch, 32x32 tiles) ---
    ConvJobs j;
    int nblk = 0, ji = 0;
    auto addjob = [&](const float* s, _Float16* d, int K, int N, int Kp) {
        j.src[ji] = s; j.dst[ji] = d; j.K[ji] = K; j.N[ji] = N; j.Kp[ji] = Kp;
        j.blk0[ji] = nblk; nblk += (N >> 5) * (Kp >> 5); ++ji;
    };
    for (int b = 0; b < 2; ++b) addjob(win[b], w.winT + b * 512 * 128, F[b], 512, 128);
    for (int b = 0; b < 2; ++b)
        for (int l = 0; l < 3; ++l)
            addjob(ws3[b] + (size_t)l * 512 * 512,
                   w.wsT + ((size_t)b * 3 + l) * 512 * 512, 512, 512, 512);
    for (int b = 0; b < 2; ++b) addjob(wo[b], w.woutT + b * 128 * 512, 512, 128, 512);
    addjob(w_fc1, w.fc1T, 256, 1024, 256);
    addjob(w_fc2, w.fc2T, 1024, 512, 1024);
    j.blk0[12] = nblk;
    conv_all<<<nblk, 256, 0, stream>>>(j);

    // --- 2. CSR build ---
    init_deg<<<dim3(NN / 256, 1, 2), 256, 0, stream>>>(w.deg);
    count_edges2<<<(EM + EP + 255) / 256, 256, 0, stream>>>(mol_ei + EM, EM, pro_ei + EP, EP, w.deg);
    scan_offsets<<<dim3(1, 1, 2), 1024, 0, stream>>>(w.deg, w.offs, w.cur, w.dis);
    scatter2<<<(EM + EP + 255) / 256, 256, 0, stream>>>(mol_ei, mol_ei + EM, EM,
                                                        pro_ei, pro_ei + EP, EP,
                                                        w.cur, w.srow0, w.srow1);

    // --- 3. branches: input GEMM (writes h0 only; layer 0 reads pin = h0 directly) ---
    auto branch_chain = [&](int zcount, int b0) {
        GArgs g{};
        for (int z = 0; z < zcount; ++z) {
            int b = b0 + z;
            g.A[z] = w.xpad + z * XSTR;
            g.BT[z] = w.winT + b * 512 * 128;
            g.bias[z] = bin[b];
            g.C[z] = w.h0 + z * BSTR;
            g.C2[z] = nullptr;                    // prev == h0 at layer 0
        }
        gemm_a1<128><<<dim3(256, 2, zcount), 512, 0, stream>>>(g, HID);
        // ping-pong: l0: h0 -> prev1; l1: prev1 -> prev0; l2: prev0 -> (fused out-proj)
        const _Float16* pins[3] = {w.h0, w.prev1, w.prev0};
        _Float16* pouts[3] = {w.prev1, w.prev0, nullptr};
        for (int l = 0; l < 3; ++l) {
            LArgs a{};
            a.pin = pins[l];
            a.h0 = w.h0;
            a.pout = pouts[l];
            a.dis = w.dis; a.offs = w.offs; a.sr0 = w.srow0; a.sr1 = w.srow1;
            a.wT = w.wsT + ((size_t)b0 * 3 + l) * 512 * 512;
            a.woutT = (l == 2) ? (w.woutT + (size_t)b0 * 128 * 512) : nullptr;
            a.bo[0] = bo[0]; a.bo[1] = bo[1];
            a.xc = w.xc;
            a.bstr = BSTR; a.mzadd = b0;
            layer_fused<<<dim3(256, 1, zcount), 1024, LDSB, stream>>>(a);
        }
    };

    if (comb) {
        pad_x2<<<dim3(NN * 128 / 256, 1, 2), 256, 0, stream>>>(mol_x, pro_x, F[0], F[1], w.xpad);
        branch_chain(2, 0);
    } else {
        for (int b = 0; b < 2; ++b) {
            pad_x2<<<dim3(NN * 128 / 256, 1, 1), 256, 0, stream>>>(
                b ? pro_x : mol_x, nullptr, F[b], 0, w.xpad);
            branch_chain(1, b);
        }
    }

    // --- 4. MLP head: x1 = relu(xc@fc1+b1); out = relu(x1@fc2+b2).w_o + b_o (fused) ---
    _Float16* x1 = w.h0;    // [NN,1024]: comb -> h0 block (64MB); fallback -> h0+prev0 contiguous
    GArgs g1{};
    g1.A[0] = w.xc; g1.BT[0] = w.fc1T; g1.bias[0] = b_fc1; g1.C[0] = x1; g1.C2[0] = nullptr;
    gemm_a1<256><<<dim3(256, 4, 1), 512, 0, stream>>>(g1, 1024);
    gemm_fc2f<<<dim3(NN / 64, 1), 512, LDSF, stream>>>(x1, w.fc2T, b_fc2, w_o, b_o, (float*)d_out);
    (void)in_sizes; (void)n_in; (void)out_size; (void)ws_size;
}

// Round 15
// 887.375 us; speedup vs baseline: 1.4443x; 1.0247x over previous
//
#include <hip/hip_runtime.h>
#include <stdint.h>

#define NN 32768            // nodes
#define HID 512
#define EM 131072           // mol edges
#define EP 196608           // pro edges
#define AS1 __attribute__((address_space(1)))
#define AS3 __attribute__((address_space(3)))

typedef _Float16 h8 __attribute__((ext_vector_type(8)));
typedef float f4 __attribute__((ext_vector_type(4)));
typedef float f8 __attribute__((ext_vector_type(8)));

__device__ __forceinline__ void gload_lds16(const _Float16* g, _Float16* l) {
    __builtin_amdgcn_global_load_lds((AS1 void*)(g), (AS3 void*)(l), 16, 0, 0);
}

// ---------------- fused weight conversion: LDS-tiled transpose+cast, 12 jobs, one launch ----
struct ConvJobs {
    const float* src[12];
    _Float16* dst[12];
    int K[12], N[12], Kp[12];
    int blk0[13];   // cumulative 32x32-tile starts
};

__global__ void conv_all(ConvJobs j) {
    __shared__ float tile[32][33];
    int blk = blockIdx.x, job = 0;
    while (blk >= j.blk0[job + 1]) ++job;
    int t = blk - j.blk0[job];
    int Kp = j.Kp[job], N = j.N[job], K = j.K[job];
    int ktiles = Kp >> 5;
    int n0 = (t / ktiles) << 5, k0 = (t % ktiles) << 5;
    int tn = threadIdx.x & 31, tr = threadIdx.x >> 5;
    const float* src = j.src[job];
    #pragma unroll
    for (int p = 0; p < 4; ++p) {
        int k = k0 + tr + p * 8;
        tile[tr + p * 8][tn] = (k < K) ? src[(size_t)k * N + n0 + tn] : 0.f;
    }
    __syncthreads();
    _Float16* dst = j.dst[job];
    #pragma unroll
    for (int p = 0; p < 4; ++p) {
        int nl = tr + p * 8;
        dst[(size_t)(n0 + nl) * Kp + k0 + tn] = (_Float16)tile[tn][nl];
    }
}

// pad+cast features fp32 [NN,F] -> fp16 [NN,128]; z selects branch (combined mode)
__global__ void pad_x2(const float* s0, const float* s1, int F0, int F1, _Float16* dstb) {
    int z = blockIdx.z;
    const float* src = z ? s1 : s0;
    int F = z ? F1 : F0;
    _Float16* dst = dstb + (size_t)z * NN * 128;
    int idx = blockIdx.x * 256 + threadIdx.x;
    int i = idx >> 7, jj = idx & 127;
    dst[idx] = (jj < F) ? (_Float16)src[(size_t)i * F + jj] : (_Float16)0.f;
}

// ---------------- CSR build (both branches, meta arrays are [2][...]) ----------------
__global__ void init_deg(int* deg) {
    deg[(size_t)blockIdx.z * NN + blockIdx.x * 256 + threadIdx.x] = 1;  // self loop
}

__global__ void count_edges2(const int* c0, int E0, const int* c1, int E1, int* deg) {
    int i = blockIdx.x * 256 + threadIdx.x;
    if (i < E0) atomicAdd(&deg[c0[i]], 1);
    else { i -= E0; if (i < E1) atomicAdd(&deg[NN + c1[i]], 1); }
}

// exclusive scan of (deg-1) + dis = rsqrt(deg); one block per branch (blockIdx.z)
__global__ void scan_offsets(const int* degb, int* offsb, int* curb, float* disb) {
    const int* deg = degb + blockIdx.z * NN;
    int* offs = offsb + blockIdx.z * (NN + 1);
    int* cur = curb + blockIdx.z * NN;
    float* dis = disb + blockIdx.z * NN;
    __shared__ int part[1024];
    int t = threadIdx.x, base = t * 32;
    int loc[32], sum = 0;
    for (int jj = 0; jj < 32; ++jj) {
        int d = deg[base + jj];
        dis[base + jj] = rsqrtf((float)d);
        loc[jj] = sum; sum += d - 1;
    }
    part[t] = sum;
    __syncthreads();
    for (int o = 1; o < 1024; o <<= 1) {
        int v = (t >= o) ? part[t - o] : 0;
        __syncthreads();
        part[t] += v;
        __syncthreads();
    }
    int pre = (t == 0) ? 0 : part[t - 1];
    for (int jj = 0; jj < 32; ++jj) { int x = pre + loc[jj]; offs[base + jj] = x; cur[base + jj] = x; }
    if (t == 1023) offs[NN] = part[1023];
}

__global__ void scatter2(const int* r0, const int* c0, int E0,
                         const int* r1, const int* c1, int E1,
                         int* cur, int* s0, int* s1) {
    int i = blockIdx.x * 256 + threadIdx.x;
    if (i < E0) { int p = atomicAdd(&cur[c0[i]], 1); s0[p] = r0[i]; }
    else { i -= E0; if (i < E1) { int p = atomicAdd(&cur[NN + c1[i]], 1); s1[p] = r1[i]; } }
}

// ---------------- fused layer: 128-row tile, 1024 threads; ALL global stores coalesced -----
// Phase 1: 16 waves gather 8 rows each into LDS. Phase 2: barrier-free GEMM (wave tile 64x64,
// B from L2-hot global). Epilogue: nv = relu(sup + sup@W) + pin written IN PLACE to sup
// (pre-barrier makes it race-safe), then a copy phase streams full 1KB rows to pout with h8
// stores (fixes the 1.8x partial-sector write amplification seen in R12/R14 counters).
// Last layer: out-projection K=512 GEMM vs woutT from sup, stash to LDS, coalesced xc copy.
#define ROWP 536

struct LArgs {
    const _Float16* pin;
    const _Float16* h0;
    _Float16* pout;            // unused when woutT != null
    const float* dis;
    const int* offs;
    const int* sr0;
    const int* sr1;
    const _Float16* wT;        // layer weight base (layer offset applied), z-stride 3*512*512
    const _Float16* woutT;     // out-proj weights base (b0 offset applied), z-stride 128*512
    const float* bo[2];        // out-proj bias per branch slot (index mz)
    _Float16* xc;              // [NN, 256]
    size_t bstr;
    int mzadd;
};

__global__ __launch_bounds__(1024, 4) void layer_fused(LArgs a) {
    extern __shared__ _Float16 sup[];   // [128][ROWP]
    const int z = blockIdx.z, mz = z + a.mzadd;
    const _Float16* __restrict__ pin = a.pin + (size_t)z * a.bstr;
    const _Float16* __restrict__ h0 = a.h0 + (size_t)z * a.bstr;
    const _Float16* __restrict__ BT = a.wT + (size_t)z * (3 * 512 * 512);
    const float* __restrict__ dis = a.dis + mz * NN;
    const int* __restrict__ offs = a.offs + mz * (NN + 1);
    const int* __restrict__ srow = mz ? a.sr1 : a.sr0;
    const int tid = threadIdx.x, wave = tid >> 6, lane = tid & 63;
    const int row0 = blockIdx.x * 128;

    // ---- phase 1: gather 8 rows per wave; 4-wide independent-load batches ----
    for (int i = 0; i < 8; ++i) {
        const int rl = wave * 8 + i, row = row0 + rl;
        const int e0 = offs[row], e1 = offs[row + 1];
        f8 acg = {};
        for (int e = e0; e < e1; e += 4) {
            const int j1 = (e + 1 < e1) ? e + 1 : e;
            const int j2 = (e + 2 < e1) ? e + 2 : e;
            const int j3 = (e + 3 < e1) ? e + 3 : e;
            const float m1 = (e + 1 < e1) ? 1.f : 0.f;
            const float m2 = (e + 2 < e1) ? 1.f : 0.f;
            const float m3 = (e + 3 < e1) ? 1.f : 0.f;
            const int r0 = srow[e], r1 = srow[j1], r2 = srow[j2], r3 = srow[j3];
            const float s0 = dis[r0], s1 = dis[r1] * m1, s2 = dis[r2] * m2, s3 = dis[r3] * m3;
            h8 v0 = *(const h8*)&pin[(size_t)r0 * 512 + lane * 8];
            h8 v1 = *(const h8*)&pin[(size_t)r1 * 512 + lane * 8];
            h8 v2 = *(const h8*)&pin[(size_t)r2 * 512 + lane * 8];
            h8 v3 = *(const h8*)&pin[(size_t)r3 * 512 + lane * 8];
            acg += s0 * __builtin_convertvector(v0, f8) + s1 * __builtin_convertvector(v1, f8)
                 + s2 * __builtin_convertvector(v2, f8) + s3 * __builtin_convertvector(v3, f8);
        }
        const float si = dis[row];
        h8 pv = *(const h8*)&pin[(size_t)row * 512 + lane * 8];
        h8 hv = *(const h8*)&h0[(size_t)row * 512 + lane * 8];
        f8 r = 0.8f * si * (acg + si * __builtin_convertvector(pv, f8))
             + 0.2f * __builtin_convertvector(hv, f8);
        *(h8*)&sup[rl * ROWP + lane * 8] = __builtin_convertvector(r, h8);
    }
    __syncthreads();

    // ---- phase 2: barrier-free GEMM; 16 waves, wave tile 64x64 (4x4 frags) ----
    const int wm = wave & 1, wn = wave >> 1;          // wn in [0,8): 64-col slice
    const int l15 = lane & 15, lq = lane >> 4;
    f4 acc[4][4] = {};
    #pragma unroll
    for (int kt = 0; kt < 8; ++kt) {
        #pragma unroll
        for (int s = 0; s < 2; ++s) {
            const int koff = kt * 64 + s * 32 + lq * 8;
            h8 af[4], bf[4];
            #pragma unroll
            for (int rt = 0; rt < 4; ++rt)
                af[rt] = *(const h8*)&sup[(wm * 64 + rt * 16 + l15) * ROWP + koff];
            #pragma unroll
            for (int ct = 0; ct < 4; ++ct)
                bf[ct] = *(const h8*)(BT + (size_t)(wn * 64 + ct * 16 + l15) * 512 + koff);
            #pragma unroll
            for (int rt = 0; rt < 4; ++rt)
                #pragma unroll
                for (int ct = 0; ct < 4; ++ct)
                    acc[rt][ct] = __builtin_amdgcn_mfma_f32_16x16x32_f16(af[rt], bf[ct], acc[rt][ct], 0, 0, 0);
        }
    }
    __syncthreads();   // all GEMM reads of sup complete before in-place overwrite

    // ---- epilogue: nv = relu(sup + sup@W) + pin -> sup (in place, own elements) ----
    #pragma unroll
    for (int rt = 0; rt < 4; ++rt) {
        #pragma unroll
        for (int ct = 0; ct < 4; ++ct) {
            const int col = wn * 64 + ct * 16 + l15;
            #pragma unroll
            for (int r = 0; r < 4; ++r) {
                const int rl = wm * 64 + rt * 16 + lq * 4 + r;
                const size_t gi = (size_t)(row0 + rl) * 512 + col;
                float nv = fmaxf((float)sup[rl * ROWP + col] + acc[rt][ct][r], 0.f) + (float)pin[gi];
                sup[rl * ROWP + col] = (_Float16)nv;
            }
        }
    }
    __syncthreads();

    const bool fuse_out = (a.woutT != nullptr);
    if (!fuse_out) {
        // ---- coalesced copy: full 1KB rows, h8 stores (64 lanes x 16B = one row/instr) ----
        _Float16* __restrict__ pout = a.pout + (size_t)z * a.bstr;
        #pragma unroll
        for (int i = 0; i < 8; ++i) {
            const int rl = wave * 8 + i;
            *(h8*)&pout[(size_t)(row0 + rl) * 512 + lane * 8] =
                *(const h8*)&sup[rl * ROWP + lane * 8];
        }
        return;
    }

    // ---- fused out-projection: xc[:, mz*128 : +128] = sup_final @ woutT + bo ----
    const _Float16* __restrict__ WO = a.woutT + (size_t)z * (128 * 512);
    const float* __restrict__ bo = a.bo[mz];
    f4 acc2[4] = {};                                  // 4 row frags x 1 col frag (16 cols/wave)
    #pragma unroll
    for (int kt = 0; kt < 8; ++kt) {
        #pragma unroll
        for (int s = 0; s < 2; ++s) {
            const int koff = kt * 64 + s * 32 + lq * 8;
            h8 af[4];
            #pragma unroll
            for (int rt = 0; rt < 4; ++rt)
                af[rt] = *(const h8*)&sup[(wm * 64 + rt * 16 + l15) * ROWP + koff];
            h8 bf = *(const h8*)(WO + (size_t)(wn * 16 + l15) * 512 + koff);
            #pragma unroll
            for (int rt = 0; rt < 4; ++rt)
                acc2[rt] = __builtin_amdgcn_mfma_f32_16x16x32_f16(af[rt], bf, acc2[rt], 0, 0, 0);
        }
    }
    __syncthreads();   // out-proj reads of sup done before stash overwrites
    // stash results [128 rows][128 cols] at stride 136 halfs (16B-aligned rows)
    #pragma unroll
    for (int rt = 0; rt < 4; ++rt) {
        const int col = wn * 16 + l15;
        #pragma unroll
        for (int r = 0; r < 4; ++r) {
            const int rl = wm * 64 + rt * 16 + lq * 4 + r;
            sup[rl * 136 + col] = (_Float16)(acc2[rt][r] + bo[col]);
        }
    }
    __syncthreads();
    // coalesced xc copy: 4 rows per instr (16 lanes x h8 per row = 256B)
    #pragma unroll
    for (int i = 0; i < 2; ++i) {
        const int rl = wave * 8 + i * 4 + (lane >> 4);
        const int co = lane & 15;
        *(h8*)&a.xc[(size_t)(row0 + rl) * 256 + mz * 128 + co * 8] =
            *(const h8*)&sup[rl * 136 + co * 8];
    }
}

// ---------------- staged-A barrier-free GEMM (K<=256): C = relu(A@B^T + bias) ---------------
struct GArgs {
    const _Float16* A[2];
    const _Float16* BT[2];
    const float* bias[2];
    _Float16* C[2];
    _Float16* C2[2];
};

template <int K>
__global__ __launch_bounds__(512, 4) void gemm_a1(GArgs g, int ldc) {
    constexpr int NK = K / 64;
    __shared__ _Float16 lA[NK * 8 * 128 * 8];
    const int z = blockIdx.z;
    const _Float16* __restrict__ A = g.A[z];
    const _Float16* __restrict__ BT = g.BT[z];
    const int tid = threadIdx.x, wave = tid >> 6, lane = tid & 63;
    const int row0 = blockIdx.x * 128, col0 = blockIdx.y * 256;
    const int wm = wave & 1, wn = wave >> 1;          // 8 waves: 2 x 4, wave tile 64x64
    const int l15 = lane & 15, lq = lane >> 4;
    constexpr int CNT = NK * 16 / 8;                  // staging instrs per wave
    #pragma unroll
    for (int q = 0; q < CNT; ++q) {
        const int c = wave * CNT + q;
        const int kc = c >> 4, rem = c & 15, k8 = rem & 7, rh = rem >> 3;
        gload_lds16(A + (size_t)(row0 + rh * 64 + lane) * K + kc * 64 + k8 * 8,
                    &lA[((kc * 8 + k8) * 128 + rh * 64) * 8]);
    }
    __syncthreads();
    f4 acc[4][4] = {};
    #pragma unroll
    for (int kt = 0; kt < NK; ++kt) {
        #pragma unroll
        for (int s = 0; s < 2; ++s) {
            const int kq = s * 4 + lq;
            h8 af[4], bf[4];
            #pragma unroll
            for (int rt = 0; rt < 4; ++rt)
                af[rt] = *(const h8*)&lA[((kt * 8 + kq) * 128 + wm * 64 + rt * 16 + l15) * 8];
            #pragma unroll
            for (int ct = 0; ct < 4; ++ct)
                bf[ct] = *(const h8*)(BT + (size_t)(col0 + wn * 64 + ct * 16 + l15) * K + kt * 64 + kq * 8);
            #pragma unroll
            for (int rt = 0; rt < 4; ++rt)
                #pragma unroll
                for (int ct = 0; ct < 4; ++ct)
                    acc[rt][ct] = __builtin_amdgcn_mfma_f32_16x16x32_f16(af[rt], bf[ct], acc[rt][ct], 0, 0, 0);
        }
    }
    #pragma unroll
    for (int rt = 0; rt < 4; ++rt) {
        #pragma unroll
        for (int ct = 0; ct < 4; ++ct) {
            const int col = col0 + wn * 64 + ct * 16 + l15;
            #pragma unroll
            for (int r = 0; r < 4; ++r) {
                const int row = row0 + wm * 64 + rt * 16 + lq * 4 + r;
                float v = fmaxf(acc[rt][ct][r] + g.bias[z][col], 0.f);
                g.C[z][(size_t)row * ldc + col] = (_Float16)v;
                if (g.C2[z]) g.C2[z][(size_t)row * ldc + col] = (_Float16)v;
            }
        }
    }
}

// ---------------- fc2 + final dot, staged-A barrier-free, deterministic LDS reduction ------
__global__ __launch_bounds__(512, 2) void gemm_fc2f(
    const _Float16* __restrict__ A, const _Float16* __restrict__ BT,
    const float* __restrict__ b2, const float* __restrict__ wo,
    const float* __restrict__ bo, float* __restrict__ out) {
    extern __shared__ _Float16 lA[];                  // [128 k-octs][64 rows][8] + part[64][4]
    float* part = (float*)(lA + 64 * 1024);
    const int tid = threadIdx.x, wave = tid >> 6, lane = tid & 63;
    const int row0 = blockIdx.x * 64;
    const int wm = wave & 1, wn = wave >> 1;          // 8 waves: 2 x 4; wave tile 32x128
    const int l15 = lane & 15, lq = lane >> 4;
    #pragma unroll
    for (int q = 0; q < 16; ++q) {
        const int c = wave * 16 + q;                  // k-oct index
        gload_lds16(A + (size_t)(row0 + lane) * 1024 + c * 8, &lA[(c * 64) * 8]);
    }
    __syncthreads();
    f4 acc[2][8] = {};
    #pragma unroll
    for (int kt = 0; kt < 32; ++kt) {                 // K = 1024, 32-wide steps
        const int ko = kt * 4 + lq;
        h8 af[2], bf[8];
        #pragma unroll
        for (int rt = 0; rt < 2; ++rt)
            af[rt] = *(const h8*)&lA[(ko * 64 + wm * 32 + rt * 16 + l15) * 8];
        #pragma unroll
        for (int ct = 0; ct < 8; ++ct)
            bf[ct] = *(const h8*)(BT + (size_t)(wn * 128 + ct * 16 + l15) * 1024 + kt * 32 + lq * 8);
        #pragma unroll
        for (int rt = 0; rt < 2; ++rt)
            #pragma unroll
            for (int ct = 0; ct < 8; ++ct)
                acc[rt][ct] = __builtin_amdgcn_mfma_f32_16x16x32_f16(af[rt], bf[ct], acc[rt][ct], 0, 0, 0);
    }
    #pragma unroll
    for (int rt = 0; rt < 2; ++rt) {
        #pragma unroll
        for (int r = 0; r < 4; ++r) {
            float p = 0.f;
            #pragma unroll
            for (int ct = 0; ct < 8; ++ct) {
                const int colg = wn * 128 + ct * 16 + l15;
                float v = fmaxf(acc[rt][ct][r] + b2[colg], 0.f);
                p += v * wo[colg];
            }
            p += __shfl_xor(p, 1); p += __shfl_xor(p, 2);
            p += __shfl_xor(p, 4); p += __shfl_xor(p, 8);
            if (l15 == 0) {
                const int rl = wm * 32 + rt * 16 + lq * 4 + r;
                part[rl * 4 + wn] = p;
            }
        }
    }
    __syncthreads();
    if (tid < 64)
        out[row0 + tid] = part[tid * 4] + part[tid * 4 + 1] + part[tid * 4 + 2]
                        + part[tid * 4 + 3] + bo[0];
}

// ---------------- workspace plan ----------------
struct WS {
    int *deg, *offs, *cur, *srow0, *srow1;
    float* dis;
    _Float16 *winT, *wsT, *woutT, *fc1T, *fc2T;
    _Float16 *xpad, *h0, *prev0, *prev1, *xc;
    size_t total;
};

static WS plan(char* base, bool comb) {
    size_t off = 0;
    auto al = [&](size_t n) { off = (off + 255) & ~(size_t)255; size_t o = off; off += n; return base + o; };
    WS w;
    w.deg   = (int*)al(2 * NN * 4);
    w.dis   = (float*)al(2 * NN * 4);
    w.offs  = (int*)al(2 * (NN + 1) * 4);
    w.cur   = (int*)al(2 * NN * 4);
    w.srow0 = (int*)al((size_t)EM * 4);
    w.srow1 = (int*)al((size_t)EP * 4);
    w.winT  = (_Float16*)al(2 * 512 * 128 * 2);
    w.wsT   = (_Float16*)al((size_t)2 * 3 * 512 * 512 * 2);
    w.woutT = (_Float16*)al(2 * 128 * 512 * 2);
    w.fc1T  = (_Float16*)al(1024 * 256 * 2);
    w.fc2T  = (_Float16*)al((size_t)512 * 1024 * 2);
    const size_t nb = comb ? 2 : 1;
    const size_t HB = (size_t)NN * HID * 2;      // 32 MB, 256-aligned -> h0/prev0 contiguous
    w.xpad  = (_Float16*)al(nb * NN * 128 * 2);
    w.h0    = (_Float16*)al(nb * HB);            // reused as x1 [NN,1024] in the head
    w.prev0 = (_Float16*)al(nb * HB);
    w.prev1 = (_Float16*)al(nb * HB);
    w.xc    = (_Float16*)al((size_t)NN * 256 * 2);
    w.total = off;
    return w;
}

// ---------------- host orchestration ----------------
extern "C" void kernel_launch(void* const* d_in, const int* in_sizes, int n_in,
                              void* d_out, int out_size, void* d_ws, size_t ws_size,
                              hipStream_t stream) {
    const float* mol_x   = (const float*)d_in[0];
    const int*   mol_ei  = (const int*)d_in[1];
    const float* pro_x   = (const float*)d_in[2];
    const int*   pro_ei  = (const int*)d_in[3];
    const float* win[2]  = {(const float*)d_in[4], (const float*)d_in[9]};
    const float* bin[2]  = {(const float*)d_in[5], (const float*)d_in[10]};
    const float* ws3[2]  = {(const float*)d_in[6], (const float*)d_in[11]};
    const float* wo[2]   = {(const float*)d_in[7], (const float*)d_in[12]};
    const float* bo[2]   = {(const float*)d_in[8], (const float*)d_in[13]};
    const float* w_fc1   = (const float*)d_in[14];
    const float* b_fc1   = (const float*)d_in[15];
    const float* w_fc2   = (const float*)d_in[16];
    const float* b_fc2   = (const float*)d_in[17];
    const float* w_o     = (const float*)d_in[18];
    const float* b_o     = (const float*)d_in[19];
    const int F[2] = {78, 54};

    char* wsb = (char*)d_ws;
    WS w = plan(wsb, true);
    const bool comb = (w.total <= ws_size);
    if (!comb) w = plan(wsb, false);
    const size_t BSTR = comb ? (size_t)NN * HID : 0;
    const size_t XSTR = comb ? (size_t)NN * 128 : 0;
    const int LDSB = 128 * ROWP * 2;                // 137216 B dynamic LDS (1 block/CU)
    const int LDSF = 64 * 1024 * 2 + 64 * 4 * 4;    // fc2f A-slab + part[64][4]

    hipFuncSetAttribute((const void*)layer_fused,
                        hipFuncAttributeMaxDynamicSharedMemorySize, LDSB);
    hipFuncSetAttribute((const void*)gemm_fc2f,
                        hipFuncAttributeMaxDynamicSharedMemorySize, LDSF);

    // --- 1. weight conversions (12 jobs, one launch, 32x32 tiles) ---
    ConvJobs j;
    int nblk = 0, ji = 0;
    auto addjob = [&](const float* s, _Float16* d, int K, int N, int Kp) {
        j.src[ji] = s; j.dst[ji] = d; j.K[ji] = K; j.N[ji] = N; j.Kp[ji] = Kp;
        j.blk0[ji] = nblk; nblk += (N >> 5) * (Kp >> 5); ++ji;
    };
    for (int b = 0; b < 2; ++b) addjob(win[b], w.winT + b * 512 * 128, F[b], 512, 128);
    for (int b = 0; b < 2; ++b)
        for (int l = 0; l < 3; ++l)
            addjob(ws3[b] + (size_t)l * 512 * 512,
                   w.wsT + ((size_t)b * 3 + l) * 512 * 512, 512, 512, 512);
    for (int b = 0; b < 2; ++b) addjob(wo[b], w.woutT + b * 128 * 512, 512, 128, 512);
    addjob(w_fc1, w.fc1T, 256, 1024, 256);
    addjob(w_fc2, w.fc2T, 1024, 512, 1024);
    j.blk0[12] = nblk;
    conv_all<<<nblk, 256, 0, stream>>>(j);

    // --- 2. CSR build ---
    init_deg<<<dim3(NN / 256, 1, 2), 256, 0, stream>>>(w.deg);
    count_edges2<<<(EM + EP + 255) / 256, 256, 0, stream>>>(mol_ei + EM, EM, pro_ei + EP, EP, w.deg);
    scan_offsets<<<dim3(1, 1, 2), 1024, 0, stream>>>(w.deg, w.offs, w.cur, w.dis);
    scatter2<<<(EM + EP + 255) / 256, 256, 0, stream>>>(mol_ei, mol_ei + EM, EM,
                                                        pro_ei, pro_ei + EP, EP,
                                                        w.cur, w.srow0, w.srow1);

    // --- 3. branches: input GEMM (writes h0 only; layer 0 reads pin = h0 directly) ---
    auto branch_chain = [&](int zcount, int b0) {
        GArgs g{};
        for (int z = 0; z < zcount; ++z) {
            int b = b0 + z;
            g.A[z] = w.xpad + z * XSTR;
            g.BT[z] = w.winT + b * 512 * 128;
            g.bias[z] = bin[b];
            g.C[z] = w.h0 + z * BSTR;
            g.C2[z] = nullptr;                    // prev == h0 at layer 0
        }
        gemm_a1<128><<<dim3(256, 2, zcount), 512, 0, stream>>>(g, HID);
        // ping-pong: l0: h0 -> prev1; l1: prev1 -> prev0; l2: prev0 -> (fused out-proj)
        const _Float16* pins[3] = {w.h0, w.prev1, w.prev0};
        _Float16* pouts[3] = {w.prev1, w.prev0, nullptr};
        for (int l = 0; l < 3; ++l) {
            LArgs a{};
            a.pin = pins[l];
            a.h0 = w.h0;
            a.pout = pouts[l];
            a.dis = w.dis; a.offs = w.offs; a.sr0 = w.srow0; a.sr1 = w.srow1;
            a.wT = w.wsT + ((size_t)b0 * 3 + l) * 512 * 512;
            a.woutT = (l == 2) ? (w.woutT + (size_t)b0 * 128 * 512) : nullptr;
            a.bo[0] = bo[0]; a.bo[1] = bo[1];
            a.xc = w.xc;
            a.bstr = BSTR; a.mzadd = b0;
            layer_fused<<<dim3(256, 1, zcount), 1024, LDSB, stream>>>(a);
        }
    };

    if (comb) {
        pad_x2<<<dim3(NN * 128 / 256, 1, 2), 256, 0, stream>>>(mol_x, pro_x, F[0], F[1], w.xpad);
        branch_chain(2, 0);
    } else {
        for (int b = 0; b < 2; ++b) {
            pad_x2<<<dim3(NN * 128 / 256, 1, 1), 256, 0, stream>>>(
                b ? pro_x : mol_x, nullptr, F[b], 0, w.xpad);
            branch_chain(1, b);
        }
    }

    // --- 4. MLP head: x1 = relu(xc@fc1+b1); out = relu(x1@fc2+b2).w_o + b_o (fused) ---
    _Float16* x1 = w.h0;    // [NN,1024]: comb -> h0 block (64MB); fallback -> h0+prev0 contiguous
    GArgs g1{};
    g1.A[0] = w.xc; g1.BT[0] = w.fc1T; g1.bias[0] = b_fc1; g1.C[0] = x1; g1.C2[0] = nullptr;
    gemm_a1<256><<<dim3(256, 4, 1), 512, 0, stream>>>(g1, 1024);
    gemm_fc2f<<<dim3(NN / 64, 1), 512, LDSF, stream>>>(x1, w.fc2T, b_fc2, w_o, b_o, (float*)d_out);
    (void)in_sizes; (void)n_in; (void)out_size; (void)ws_size;
}